// Round 11
// baseline (422.302 us; speedup 1.0000x reference)
//
#include <hip/hip_runtime.h>
#include <hip/hip_bf16.h>
#include <hip/hip_fp16.h>

#define DIM 64
#define NPART 8
#define REP 8

typedef _Float16 half2_t __attribute__((ext_vector_type(2)));

#if defined(__has_builtin)
#if __has_builtin(__builtin_amdgcn_fdot2)
#define HAVE_FDOT2 1
#endif
#endif

__device__ __forceinline__ float dot2acc(unsigned int mu, unsigned int wu, float acc) {
#ifdef HAVE_FDOT2
    return __builtin_amdgcn_fdot2(__builtin_bit_cast(half2_t, mu),
                                  __builtin_bit_cast(half2_t, wu), acc, false);
#else
    const float2 mf = __half22float2(*(const __half2*)&mu);
    const float2 wf = __half22float2(*(const __half2*)&wu);
    return acc + mf.x * wf.x + mf.y * wf.y;
#endif
}

// ---------------------------------------------------------------------------
// K1: fused setup — x->fp16, W->packed half2, zero cnt + the 128-int counter
// block (binCnt[64] | bumpP[8] | partTot[8] | pad).
// ---------------------------------------------------------------------------
__global__ void __launch_bounds__(256) setup_kernel(
    const float4* __restrict__ x, ushort4* __restrict__ xh4,
    const float2* __restrict__ W2, unsigned int* __restrict__ wh2,
    int* __restrict__ cnt, int* __restrict__ ctrs, int n4, int n) {
    const int i = blockIdx.x * 256 + threadIdx.x;
    if (i < n4) {
        const float4 v = x[i];
        ushort4 o;
        o.x = __half_as_ushort(__float2half(v.x));
        o.y = __half_as_ushort(__float2half(v.y));
        o.z = __half_as_ushort(__float2half(v.z));
        o.w = __half_as_ushort(__float2half(v.w));
        xh4[i] = o;
    }
    if (i < DIM * DIM / 2) {
        const float2 f = W2[i];
        const __half2 h = __floats2half2_rn(f.x, f.y);
        wh2[i] = *(const unsigned int*)&h;
    }
    if (i < (n >> 2)) ((int4*)cnt)[i] = make_int4(0, 0, 0, 0);
    if (i == 0) for (int k = n & ~3; k < n; ++k) cnt[k] = 0;
    if (i < 32) ((int4*)ctrs)[i] = make_int4(0, 0, 0, 0);
}

// ---------------------------------------------------------------------------
// K2 (tier A): ballot multi-split binning — NO LDS atomics. Per edge slot:
// 3 ballots give each lane its same-bin mask (rank = popc below); lanes 0-7
// own one bin each, accumulate counts over the 4 slots, and do ONE global
// atomicAdd per (bin,wave) into replicated counters binCnt[bin*REP+rep].
// Also histograms rows into cnt (global, no-return atomics).
// ---------------------------------------------------------------------------
__global__ void __launch_bounds__(256) prep_ms_kernel(
    const void* __restrict__ eiv, int* __restrict__ cnt,
    uint2* __restrict__ bins, int* __restrict__ binCnt,
    int nE, int bound, int subcap) {
    __shared__ int sIs64;
    const int tid = threadIdx.x;
    if (tid < 64) {
        const unsigned int hi = ((const unsigned int*)eiv)[2 * tid + 1];
        const unsigned long long ball = __ballot(hi != 0u);
        if (tid == 0) sIs64 = (ball == 0ULL) ? 1 : 0;
    }
    __syncthreads();
    const int is64 = sIs64;
    const int lane = tid & 63;
    const unsigned long long below = (1ULL << lane) - 1ULL;
    const int rep  = blockIdx.x & (REP - 1);
    const int base = (blockIdx.x * 256 + tid) * 4;
    int nv = nE - base; nv = nv < 0 ? 0 : (nv > 4 ? 4 : nv);

    int r[4] = {0, 0, 0, 0}, c[4] = {0, 0, 0, 0};
    if (nv == 4) {
        if (is64) {
            const long long* ei = (const long long*)eiv;
            const longlong2 r01 = *(const longlong2*)&ei[base];
            const longlong2 r23 = *(const longlong2*)&ei[base + 2];
            const longlong2 c01 = *(const longlong2*)&ei[nE + base];
            const longlong2 c23 = *(const longlong2*)&ei[nE + base + 2];
            r[0] = (int)r01.x; r[1] = (int)r01.y; r[2] = (int)r23.x; r[3] = (int)r23.y;
            c[0] = (int)c01.x; c[1] = (int)c01.y; c[2] = (int)c23.x; c[3] = (int)c23.y;
        } else {
            const int* ei = (const int*)eiv;
            const int4 rr = *(const int4*)&ei[base];
            const int4 cc = *(const int4*)&ei[nE + base];
            r[0] = rr.x; r[1] = rr.y; r[2] = rr.z; r[3] = rr.w;
            c[0] = cc.x; c[1] = cc.y; c[2] = cc.z; c[3] = cc.w;
        }
    } else if (nv > 0) {
        for (int k = 0; k < nv; ++k) {
            if (is64) {
                const long long* ei = (const long long*)eiv;
                r[k] = (int)ei[base + k]; c[k] = (int)ei[nE + base + k];
            } else {
                const int* ei = (const int*)eiv;
                r[k] = ei[base + k]; c[k] = ei[nE + base + k];
            }
        }
    }

    int pp[4], rank[4], myCnt[4];
    #pragma unroll
    for (int k = 0; k < 4; ++k) {
        const bool valid = k < nv;
        int p = r[k] / bound; if (p > NPART - 1) p = NPART - 1;
        if (!valid) p = 0;
        pp[k] = p;
        const unsigned long long vm = __ballot(valid);
        const unsigned long long m0 = __ballot(valid && (p & 1));
        const unsigned long long m1 = __ballot(valid && (p & 2));
        const unsigned long long m2 = __ballot(valid && (p & 4));
        const unsigned long long s =
            vm & ((p & 1) ? m0 : ~m0) & ((p & 2) ? m1 : ~m1) & ((p & 4) ? m2 : ~m2);
        rank[k] = (int)__popcll(s & below);
        const int i = lane;                     // owner-lane bin (lanes 0-7)
        const unsigned long long si =
            vm & ((i & 1) ? m0 : ~m0) & ((i & 2) ? m1 : ~m1) & ((i & 4) ? m2 : ~m2);
        myCnt[k] = (int)__popcll(si);
    }
    const int pre0 = 0;
    const int pre1 = myCnt[0];
    const int pre2 = pre1 + myCnt[1];
    const int pre3 = pre2 + myCnt[2];
    const int tot  = pre3 + myCnt[3];
    int wbase = 0;
    if (lane < NPART && tot > 0)
        wbase = atomicAdd(&binCnt[lane * REP + rep], tot);
    int bb[4];
    bb[0] = __shfl(wbase + pre0, pp[0]);
    bb[1] = __shfl(wbase + pre1, pp[1]);
    bb[2] = __shfl(wbase + pre2, pp[2]);
    bb[3] = __shfl(wbase + pre3, pp[3]);
    #pragma unroll
    for (int k = 0; k < 4; ++k) {
        if (k < nv) {
            const int idx = bb[k] + rank[k];
            if (idx < subcap)
                bins[(size_t)(pp[k] * REP + rep) * subcap + idx] =
                    make_uint2((unsigned)r[k], (unsigned)c[k]);
            atomicAdd(&cnt[r[k]], 1);
        }
    }
}

// ---------------------------------------------------------------------------
// K2 (tier B): convert + histogram + partition totals (no bins).
// ---------------------------------------------------------------------------
__global__ void __launch_bounds__(256) prep32_kernel(
    const void* __restrict__ eiv, int* __restrict__ rows32, int* __restrict__ cols32,
    int* __restrict__ cnt, int* __restrict__ partTot, int nE, int bound) {
    __shared__ int lcnt[NPART], sIs64;
    const int tid = threadIdx.x;
    if (tid < NPART) lcnt[tid] = 0;
    if (tid < 64) {
        const unsigned int hi = ((const unsigned int*)eiv)[2 * tid + 1];
        const unsigned long long ball = __ballot(hi != 0u);
        if (tid == 0) sIs64 = (ball == 0ULL) ? 1 : 0;
    }
    __syncthreads();
    const int is64 = sIs64;
    const int base = (blockIdx.x * 256 + tid) * 4;
    int r[4], c[4];
    int nv = 0;
    if (base < nE) {
        nv = nE - base; if (nv > 4) nv = 4;
        if (nv == 4) {
            if (is64) {
                const long long* ei = (const long long*)eiv;
                const longlong2 r01 = *(const longlong2*)&ei[base];
                const longlong2 r23 = *(const longlong2*)&ei[base + 2];
                const longlong2 c01 = *(const longlong2*)&ei[nE + base];
                const longlong2 c23 = *(const longlong2*)&ei[nE + base + 2];
                r[0] = (int)r01.x; r[1] = (int)r01.y; r[2] = (int)r23.x; r[3] = (int)r23.y;
                c[0] = (int)c01.x; c[1] = (int)c01.y; c[2] = (int)c23.x; c[3] = (int)c23.y;
            } else {
                const int* ei = (const int*)eiv;
                const int4 rr = *(const int4*)&ei[base];
                const int4 cc = *(const int4*)&ei[nE + base];
                r[0] = rr.x; r[1] = rr.y; r[2] = rr.z; r[3] = rr.w;
                c[0] = cc.x; c[1] = cc.y; c[2] = cc.z; c[3] = cc.w;
            }
            *(int4*)&rows32[base] = make_int4(r[0], r[1], r[2], r[3]);
            *(int4*)&cols32[base] = make_int4(c[0], c[1], c[2], c[3]);
        } else {
            for (int k = 0; k < nv; ++k) {
                if (is64) {
                    const long long* ei = (const long long*)eiv;
                    r[k] = (int)ei[base + k]; c[k] = (int)ei[nE + base + k];
                } else {
                    const int* ei = (const int*)eiv;
                    r[k] = ei[base + k]; c[k] = ei[nE + base + k];
                }
                rows32[base + k] = r[k]; cols32[base + k] = c[k];
            }
        }
    }
    #pragma unroll
    for (int k = 0; k < 4; ++k) {
        if (k < nv) {
            int p = r[k] / bound; if (p > NPART - 1) p = NPART - 1;
            atomicAdd(&lcnt[p], 1);
            atomicAdd(&cnt[r[k]], 1);
        }
    }
    __syncthreads();
    if (tid < NPART && lcnt[tid] > 0) atomicAdd(&partTot[tid], lcnt[tid]);
}

// ---------------------------------------------------------------------------
// K3: segment allocation. pt = per-partition totals with ptStride entries
// each (tier A: binCnt, stride REP; tier B: partTot, stride 1).
// ---------------------------------------------------------------------------
__global__ void __launch_bounds__(256) alloc_kernel(
    const int* __restrict__ cnt, int* __restrict__ cursor,
    const int* __restrict__ pt, int ptStride, int* __restrict__ bumpP,
    int n, int bound) {
    const int gid  = blockIdx.x * 256 + threadIdx.x;
    const int lane = threadIdx.x & 63;
    const bool act = gid < n;
    const int v = act ? cnt[gid] : 0;
    int inc = v;
    #pragma unroll
    for (int off = 1; off < 64; off <<= 1) {
        const int t = __shfl_up(inc, off);
        if (lane >= off) inc += t;
    }
    const int total = __shfl(inc, 63);
    const int excl  = inc - v;
    const int rr = act ? gid : (n - 1);
    int p = rr / bound; if (p > NPART - 1) p = NPART - 1;
    p = __builtin_amdgcn_readfirstlane(p);
    int wbase = 0;
    if (lane == 0) {
        int pb = 0;
        for (int q = 0; q < p; ++q)
            for (int j = 0; j < ptStride; ++j) pb += pt[q * ptStride + j];
        wbase = pb + atomicAdd(&bumpP[p], total);
    }
    wbase = __shfl(wbase, 0);
    if (act) cursor[gid] = wbase + excl;
}

// ---------------------------------------------------------------------------
// K4 (tier A): build from the 64 sub-bins; partition p = blockIdx&7 keeps its
// cursor slice / scol region XCD-local. After this, cursor[r] == segment end.
// ---------------------------------------------------------------------------
__global__ void __launch_bounds__(256) build_bin_kernel(
    const uint2* __restrict__ bins, const int* __restrict__ binCnt,
    int* __restrict__ cursor, int* __restrict__ scol, int subcap) {
    const int p  = blockIdx.x & (NPART - 1);
    const int bq = blockIdx.x >> 3;
    const int nb = gridDim.x >> 3;
    for (int rep = 0; rep < REP; ++rep) {
        int m = binCnt[p * REP + rep];
        if (m > subcap) m = subcap;
        const uint2* bp = bins + (size_t)(p * REP + rep) * subcap;
        for (int i = bq * 256 + (int)threadIdx.x; i < m; i += nb * 256) {
            const uint2 rc = bp[i];
            const int pos = atomicAdd(&cursor[rc.x], 1);
            scol[pos] = (int)rc.y;
        }
    }
}

// K4 (tier B): 8-pass partitioned build from rows32/cols32.
__global__ void __launch_bounds__(256) build_part32_kernel(
    const int* __restrict__ rows32, const int* __restrict__ cols32,
    int* __restrict__ cursor, int* __restrict__ scol, int nE, int bound) {
    const int p  = blockIdx.x & (NPART - 1);
    const int q  = blockIdx.x / NPART;
    const int nq = gridDim.x / NPART;
    const unsigned lo = (unsigned)p * (unsigned)bound;
    const unsigned bnd = (unsigned)((p == NPART - 1) ? 0x7fffffff : bound);
    const int stride = nq * 256;
    for (int e = q * 256 + (int)threadIdx.x; e < nE; e += stride) {
        const int r = rows32[e];
        if ((unsigned)r - lo < bnd) {
            const int pos = atomicAdd(&cursor[r], 1);
            scol[pos] = cols32[e];
        }
    }
}

// ---------------------------------------------------------------------------
// K5: fused gather (fp16, quarter-wave, 16 edges in flight) + mean +
// dot(W fp16 pinned in VGPRs, v_dot2_f32_f16) + bias. One wave per node.
// ---------------------------------------------------------------------------
__global__ void __launch_bounds__(256) gather_finalize_q_kernel(
    const __half* __restrict__ xh, const int* __restrict__ scol,
    const int* __restrict__ cursor, const int* __restrict__ cnt,
    const unsigned int* __restrict__ wh2, const float* __restrict__ b,
    float* __restrict__ out, int n) {
    __shared__ __align__(16) unsigned int rowh[4][32];   // fp16 mean row per wave
    const int tid   = threadIdx.x;
    const int group = tid >> 6;
    const int lane  = tid & 63;
    const int q     = lane >> 4;       // quarter-wave 0..3
    const int s16   = lane & 15;       // owns features 4*s16..+3
    const int wid   = (int)((blockIdx.x * 256 + tid) >> 6);
    const int nw    = (int)((gridDim.x * 256) >> 6);

    unsigned int wcu[32];
    #pragma unroll
    for (int i = 0; i < 32; ++i) wcu[i] = wh2[lane * 32 + i];
    #pragma unroll
    for (int i = 0; i < 32; ++i) asm volatile("" : "+v"(wcu[i]));

    const float bl = b[lane];

    for (int r0 = wid; r0 < n; r0 += nw) {
        const int r   = __builtin_amdgcn_readfirstlane(r0);
        const int k   = cnt[r];
        const int end = cursor[r];
        const int s   = end - k;
        float a0 = 0.f, a1 = 0.f, a2 = 0.f, a3 = 0.f;
        int j = 0;
        for (; j + 15 < k; j += 16) {
            const int cA = scol[s + j + q];
            const int cB = scol[s + j + 4 + q];
            const int cC = scol[s + j + 8 + q];
            const int cD = scol[s + j + 12 + q];
            const uint2 uA = *(const uint2*)(xh + ((size_t)cA << 6) + (s16 << 2));
            const uint2 uB = *(const uint2*)(xh + ((size_t)cB << 6) + (s16 << 2));
            const uint2 uC = *(const uint2*)(xh + ((size_t)cC << 6) + (s16 << 2));
            const uint2 uD = *(const uint2*)(xh + ((size_t)cD << 6) + (s16 << 2));
            float2 f;
            f = __half22float2(*(const __half2*)&uA.x); a0 += f.x; a1 += f.y;
            f = __half22float2(*(const __half2*)&uA.y); a2 += f.x; a3 += f.y;
            f = __half22float2(*(const __half2*)&uB.x); a0 += f.x; a1 += f.y;
            f = __half22float2(*(const __half2*)&uB.y); a2 += f.x; a3 += f.y;
            f = __half22float2(*(const __half2*)&uC.x); a0 += f.x; a1 += f.y;
            f = __half22float2(*(const __half2*)&uC.y); a2 += f.x; a3 += f.y;
            f = __half22float2(*(const __half2*)&uD.x); a0 += f.x; a1 += f.y;
            f = __half22float2(*(const __half2*)&uD.y); a2 += f.x; a3 += f.y;
        }
        for (; j + 7 < k; j += 8) {
            const int cA = scol[s + j + q];
            const int cB = scol[s + j + 4 + q];
            const uint2 uA = *(const uint2*)(xh + ((size_t)cA << 6) + (s16 << 2));
            const uint2 uB = *(const uint2*)(xh + ((size_t)cB << 6) + (s16 << 2));
            float2 f;
            f = __half22float2(*(const __half2*)&uA.x); a0 += f.x; a1 += f.y;
            f = __half22float2(*(const __half2*)&uA.y); a2 += f.x; a3 += f.y;
            f = __half22float2(*(const __half2*)&uB.x); a0 += f.x; a1 += f.y;
            f = __half22float2(*(const __half2*)&uB.y); a2 += f.x; a3 += f.y;
        }
        if (j + 3 < k) {
            const int cA = scol[s + j + q];
            const uint2 uA = *(const uint2*)(xh + ((size_t)cA << 6) + (s16 << 2));
            float2 f;
            f = __half22float2(*(const __half2*)&uA.x); a0 += f.x; a1 += f.y;
            f = __half22float2(*(const __half2*)&uA.y); a2 += f.x; a3 += f.y;
            j += 4;
        }
        for (; j < k; ++j) {
            const int c = scol[s + j];
            if (q == 0) {
                const uint2 u = *(const uint2*)(xh + ((size_t)c << 6) + (s16 << 2));
                float2 f;
                f = __half22float2(*(const __half2*)&u.x); a0 += f.x; a1 += f.y;
                f = __half22float2(*(const __half2*)&u.y); a2 += f.x; a3 += f.y;
            }
        }
        a0 += __shfl_xor(a0, 16); a0 += __shfl_xor(a0, 32);
        a1 += __shfl_xor(a1, 16); a1 += __shfl_xor(a1, 32);
        a2 += __shfl_xor(a2, 16); a2 += __shfl_xor(a2, 32);
        a3 += __shfl_xor(a3, 16); a3 += __shfl_xor(a3, 32);
        const float inv = 1.0f / ((k > 0) ? (float)k : 1.0f);
        if (q == 0) {
            const __half2 m01 = __floats2half2_rn(a0 * inv, a1 * inv);
            const __half2 m23 = __floats2half2_rn(a2 * inv, a3 * inv);
            uint2 mu;
            mu.x = *(const unsigned int*)&m01;
            mu.y = *(const unsigned int*)&m23;
            *(uint2*)&rowh[group][s16 * 2] = mu;   // same-wave DS ordering
        }
        float dot = bl;
        #pragma unroll
        for (int i4 = 0; i4 < 8; ++i4) {
            const uint4 mm = *(const uint4*)&rowh[group][i4 * 4];
            dot = dot2acc(mm.x, wcu[i4 * 4 + 0], dot);
            dot = dot2acc(mm.y, wcu[i4 * 4 + 1], dot);
            dot = dot2acc(mm.z, wcu[i4 * 4 + 2], dot);
            dot = dot2acc(mm.w, wcu[i4 * 4 + 3], dot);
        }
        out[(size_t)r * DIM + lane] = dot;
    }
}

extern "C" void kernel_launch(void* const* d_in, const int* in_sizes, int n_in,
                              void* d_out, int out_size, void* d_ws, size_t ws_size,
                              hipStream_t stream) {
    const float* x  = (const float*)d_in[0];
    const void*  ei = (const void*)d_in[1];
    const float* W  = (const float*)d_in[2];
    const float* b  = (const float*)d_in[3];
    float* out = (float*)d_out;

    const int n  = in_sizes[0] / DIM;   // 100000
    const int nE = in_sizes[1] / 2;     // 1600000

    const int bound  = (((n + NPART - 1) / NPART) + 63) & ~63;          // %64==0
    const int subcap = (((nE / (NPART * REP)) * 3) / 2 + 256) & ~1;     // per sub-bin

    // ws layout (int units):
    //  cnt[n] | cursor[n] | ctrs[128]{binCnt[64],bumpP[8],partTot[8],pad} |
    //  scol[scolPad] | xh[n*32] | wh2[2048] |
    //  { bins[64*subcap uint2]  OR  rows32[nE]|cols32[nE] }
    const int scolPad = (nE + 3) & ~3;
    int* wsI     = (int*)d_ws;
    int* cnt     = wsI;
    int* cursor  = wsI + n;
    int* ctrs    = wsI + 2 * n;
    int* binCnt  = ctrs;
    int* bumpP   = ctrs + 64;
    int* partTot = ctrs + 72;
    int* scol    = wsI + 2 * n + 128;
    __half* xh   = (__half*)(scol + scolPad);
    unsigned int* wh2 = (unsigned int*)(xh + (size_t)n * DIM);
    uint2* bins  = (uint2*)(wh2 + 2048);
    int* rows32  = (int*)(wh2 + 2048);
    int* cols32  = rows32 + nE;

    const size_t base_ints = (size_t)2 * n + 128 + scolPad + (size_t)n * (DIM / 2) + 2048;
    const size_t need_A = (base_ints + (size_t)2 * NPART * REP * subcap) * sizeof(int);
    const size_t need_B = (base_ints + (size_t)2 * nE) * sizeof(int);

    const int n4 = n * DIM / 4;
    int maxi = n4;
    if (maxi < DIM * DIM / 2) maxi = DIM * DIM / 2;
    if (maxi < (n + 3) / 4) maxi = (n + 3) / 4;

    if (ws_size >= need_A) {
        setup_kernel<<<(maxi + 255) / 256, 256, 0, stream>>>(
            (const float4*)x, (ushort4*)xh, (const float2*)W, wh2, cnt, ctrs, n4, n);
        prep_ms_kernel<<<(nE + 1023) / 1024, 256, 0, stream>>>(
            ei, cnt, bins, binCnt, nE, bound, subcap);
        alloc_kernel<<<(n + 255) / 256, 256, 0, stream>>>(
            cnt, cursor, binCnt, REP, bumpP, n, bound);
        build_bin_kernel<<<2048, 256, 0, stream>>>(bins, binCnt, cursor, scol, subcap);
        gather_finalize_q_kernel<<<2048, 256, 0, stream>>>(
            xh, scol, cursor, cnt, wh2, b, out, n);
    } else if (ws_size >= need_B) {
        setup_kernel<<<(maxi + 255) / 256, 256, 0, stream>>>(
            (const float4*)x, (ushort4*)xh, (const float2*)W, wh2, cnt, ctrs, n4, n);
        prep32_kernel<<<(nE + 1023) / 1024, 256, 0, stream>>>(
            ei, rows32, cols32, cnt, partTot, nE, bound);
        alloc_kernel<<<(n + 255) / 256, 256, 0, stream>>>(
            cnt, cursor, partTot, 1, bumpP, n, bound);
        build_part32_kernel<<<2048, 256, 0, stream>>>(rows32, cols32, cursor, scol, nE, bound);
        gather_finalize_q_kernel<<<2048, 256, 0, stream>>>(
            xh, scol, cursor, cnt, wh2, b, out, n);
    }
}